// Round 3
// baseline (50.637 us; speedup 1.0000x reference)
//
#include <hip/hip_runtime.h>

// Memristor dense fwd, algebraically simplified:
//   t[b,r] = max(2*|x[b,r]|, 1e-12);  s = sign(x)
//   q      = max_w / 9  (G_OFF/k_G folded)
//   y[b,j] = 0.5 * [ sum_r s * (2^(L*gp + log2(wp+q)) - 2^(L*gn + log2(wn+q)))
//                    + (bp[j]+q)*n_pos[1024,j] - (bn[j]+q)*n_neg[1024,j] ],  L = log2(t)
// gp/gn = log2(n_param), interleaved columns (2j = pos, 2j+1 = neg).

#define N_IN 1024
#define N_OUT 512
#define NB 128
#define Z 64            // r-split across grid.z
#define RPB 16          // rows per block = N_IN / Z
#define JT 64           // j tile per block
#define BT 64           // b tile per block

__global__ void init_ws_kernel(unsigned int* ws) {
    ws[0] = __float_as_uint(0.5f);   // bias weights participate in the max
}

__global__ void max_kernel(const float* __restrict__ wp, const float* __restrict__ wn,
                           const float* __restrict__ bp, const float* __restrict__ bn,
                           unsigned int* __restrict__ ws) {
    const int NW4 = (N_IN * N_OUT) / 4;
    int i = blockIdx.x * blockDim.x + threadIdx.x;
    int stride = gridDim.x * blockDim.x;
    float m = 0.0f;
    const float4* wp4 = (const float4*)wp;
    const float4* wn4 = (const float4*)wn;
    for (int idx = i; idx < NW4; idx += stride) {
        float4 a = wp4[idx];
        float4 b = wn4[idx];
        m = fmaxf(m, fmaxf(fmaxf(a.x, a.y), fmaxf(a.z, a.w)));
        m = fmaxf(m, fmaxf(fmaxf(b.x, b.y), fmaxf(b.z, b.w)));
    }
    if (i < N_OUT) { m = fmaxf(m, bp[i]); m = fmaxf(m, bn[i]); }
    #pragma unroll
    for (int off = 32; off > 0; off >>= 1)
        m = fmaxf(m, __shfl_xor(m, off));
    if ((threadIdx.x & 63) == 0)
        atomicMax(ws, __float_as_uint(m));   // values >= 0: uint order == float order
}

__launch_bounds__(256, 4)
__global__ void memristor_main(const float* __restrict__ x,
                               const float* __restrict__ wp,
                               const float* __restrict__ wn,
                               const float* __restrict__ npar,
                               const unsigned int* __restrict__ wsmax,
                               float* __restrict__ part) {
    // Wg[r][arr][grp][4]: arr 0=log2(wp+q) 1=log2(wn+q) 2=gp 3=gn; grp XOR-swizzled by r
    __shared__ float Wg[RPB][4][16][4];   // 16 KiB
    // Lx[r][b_local][2]: (log2(t), sign). r-major => compute reads are conflict-free b128s.
    __shared__ float Lx[RPB][BT][2];      // 8 KiB

    const float q = __uint_as_float(wsmax[0]) * (1.0f / 9.0f);

    const int j0 = blockIdx.x * JT;
    const int b0 = blockIdx.y * BT;
    const int rbase = blockIdx.z * RPB;
    const int tid = threadIdx.x;

    // ---------------- staging (once per block) ----------------
    {
        // x tile: 64 b x 16 r; one float4 along r per thread
        int bl = tid >> 2;          // 0..63
        int rq = tid & 3;           // 0..3
        float4 v = *(const float4*)&x[(b0 + bl) * N_IN + rbase + rq * 4];
        float vv[4] = {v.x, v.y, v.z, v.w};
        #pragma unroll
        for (int k = 0; k < 4; ++k) {
            float val = vv[k];
            float s = (val > 0.0f) ? 1.0f : ((val < 0.0f) ? -1.0f : 0.0f);
            float t = fmaxf(2.0f * fabsf(val), 1e-12f);
            Lx[rq * 4 + k][bl][0] = __builtin_amdgcn_logf(t);   // log2
            Lx[rq * 4 + k][bl][1] = s;
        }
    }
    {
        // weights: 16 r-rows x 64 j-cols
        int rr = tid >> 4;          // 0..15
        int cg = tid & 15;          // 0..15 (4-col group)
        int pg = cg ^ rr;           // XOR swizzle
        {
            float4 a = *(const float4*)&wp[(rbase + rr) * N_OUT + j0 + cg * 4];
            *(float4*)&Wg[rr][0][pg][0] = make_float4(
                __builtin_amdgcn_logf(a.x + q), __builtin_amdgcn_logf(a.y + q),
                __builtin_amdgcn_logf(a.z + q), __builtin_amdgcn_logf(a.w + q));
        }
        {
            float4 a = *(const float4*)&wn[(rbase + rr) * N_OUT + j0 + cg * 4];
            *(float4*)&Wg[rr][1][pg][0] = make_float4(
                __builtin_amdgcn_logf(a.x + q), __builtin_amdgcn_logf(a.y + q),
                __builtin_amdgcn_logf(a.z + q), __builtin_amdgcn_logf(a.w + q));
        }
        {
            const float* nrow = &npar[(rbase + rr) * (2 * N_OUT) + 2 * j0 + cg * 8];
            float4 f0 = *(const float4*)&nrow[0];   // p0 n0 p1 n1
            float4 f1 = *(const float4*)&nrow[4];   // p2 n2 p3 n3
            *(float4*)&Wg[rr][2][pg][0] = make_float4(
                __builtin_amdgcn_logf(f0.x), __builtin_amdgcn_logf(f0.z),
                __builtin_amdgcn_logf(f1.x), __builtin_amdgcn_logf(f1.z));
            *(float4*)&Wg[rr][3][pg][0] = make_float4(
                __builtin_amdgcn_logf(f0.y), __builtin_amdgcn_logf(f0.w),
                __builtin_amdgcn_logf(f1.y), __builtin_amdgcn_logf(f1.w));
        }
    }
    __syncthreads();

    // ---------------- compute: 4b x 4j micro-tile per thread ----------------
    const int tj4 = tid & 15;       // j group (4 cols)
    const int tb4 = tid >> 4;       // 0..15
    const int bl0 = tb4 * 4;        // 4 b rows per thread

    float acc[4][4] = {};

    #pragma unroll 4
    for (int r = 0; r < RPB; ++r) {
        const float4* wrow = (const float4*)&Wg[r][0][tj4 ^ r][0];
        float4 lwp = wrow[0];
        float4 lwn = wrow[16];
        float4 gp  = wrow[32];
        float4 gn  = wrow[48];
        const float4* lxr = (const float4*)&Lx[r][bl0][0];
        float4 l01 = lxr[0];        // (L0,s0,L1,s1)
        float4 l23 = lxr[1];        // (L2,s2,L3,s3)
        float Lv[4] = {l01.x, l01.z, l23.x, l23.z};
        float Sv[4] = {l01.y, l01.w, l23.y, l23.w};
        float lwpv[4] = {lwp.x, lwp.y, lwp.z, lwp.w};
        float lwnv[4] = {lwn.x, lwn.y, lwn.z, lwn.w};
        float gpv[4]  = {gp.x, gp.y, gp.z, gp.w};
        float gnv[4]  = {gn.x, gn.y, gn.z, gn.w};
        #pragma unroll
        for (int ib = 0; ib < 4; ++ib) {
            #pragma unroll
            for (int jj = 0; jj < 4; ++jj) {
                float ep = __builtin_amdgcn_exp2f(fmaf(Lv[ib], gpv[jj], lwpv[jj]));
                float en = __builtin_amdgcn_exp2f(fmaf(Lv[ib], gnv[jj], lwnv[jj]));
                acc[ib][jj] = fmaf(Sv[ib], ep - en, acc[ib][jj]);
            }
        }
    }

    float* p0 = &part[(size_t)blockIdx.z * (NB * N_OUT) + (b0 + bl0) * N_OUT + j0 + tj4 * 4];
    #pragma unroll
    for (int ib = 0; ib < 4; ++ib)
        *(float4*)&p0[ib * N_OUT] = make_float4(acc[ib][0], acc[ib][1], acc[ib][2], acc[ib][3]);
}

__global__ void reduce_kernel(const float* __restrict__ part,
                              const float* __restrict__ bp, const float* __restrict__ bn,
                              const float* __restrict__ npar,
                              const unsigned int* __restrict__ wsmax,
                              float* __restrict__ out) {
    int g = blockIdx.x * blockDim.x + threadIdx.x;   // float4 index, 0..16383
    const float4* p4 = (const float4*)part;
    float sx = 0.f, sy = 0.f, sz = 0.f, sw = 0.f;
    #pragma unroll 8
    for (int z = 0; z < Z; ++z) {
        float4 v = p4[(size_t)z * (NB * N_OUT / 4) + g];
        sx += v.x; sy += v.y; sz += v.z; sw += v.w;
    }
    int o = g * 4;
    int j = o & (N_OUT - 1);
    const float q = __uint_as_float(wsmax[0]) * (1.0f / 9.0f);
    float4 bpv = *(const float4*)&bp[j];
    float4 bnv = *(const float4*)&bn[j];
    const float* nrow = &npar[N_IN * (2 * N_OUT) + 2 * j];
    float4 n0 = *(const float4*)&nrow[0];
    float4 n1 = *(const float4*)&nrow[4];
    sx += (bpv.x + q) * n0.x - (bnv.x + q) * n0.y;
    sy += (bpv.y + q) * n0.z - (bnv.y + q) * n0.w;
    sz += (bpv.z + q) * n1.x - (bnv.z + q) * n1.y;
    sw += (bpv.w + q) * n1.z - (bnv.w + q) * n1.w;
    ((float4*)out)[g] = make_float4(0.5f * sx, 0.5f * sy, 0.5f * sz, 0.5f * sw);
}

extern "C" void kernel_launch(void* const* d_in, const int* in_sizes, int n_in,
                              void* d_out, int out_size, void* d_ws, size_t ws_size,
                              hipStream_t stream) {
    const float* x    = (const float*)d_in[0];
    const float* wp   = (const float*)d_in[1];
    const float* wn   = (const float*)d_in[2];
    const float* bp   = (const float*)d_in[3];
    const float* bn   = (const float*)d_in[4];
    const float* npar = (const float*)d_in[5];
    float* out = (float*)d_out;
    unsigned int* wsmax = (unsigned int*)d_ws;
    float* part = (float*)d_ws + 64;   // 256 B offset; Z*65536 floats = 16 MiB scratch

    init_ws_kernel<<<1, 1, 0, stream>>>(wsmax);
    max_kernel<<<256, 256, 0, stream>>>(wp, wn, bp, bn, wsmax);

    dim3 grid(N_OUT / JT, NB / BT, Z);   // 8 x 2 x 64 = 1024 blocks -> 4/CU
    memristor_main<<<grid, 256, 0, stream>>>(x, wp, wn, npar, wsmax, part);

    reduce_kernel<<<(NB * N_OUT / 4) / 256, 256, 0, stream>>>(part, bp, bn, npar, wsmax, out);
}

// Round 4
// 46.282 us; speedup vs baseline: 1.0941x; 1.0941x over previous
//
#include <hip/hip_runtime.h>

// Memristor dense fwd, algebraically simplified:
//   t[b,r] = max(2*|x[b,r]|, 1e-12);  s = sign(x);  L = log2(t)
//   q      = max_w / 9  (G_OFF/k_G folded)
//   y[b,j] = 0.5 * [ sum_r s * (2^(L*gp + log2(wp+q)) - 2^(L*gn + log2(wn+q)))
//                    + (bp[j]+q)*n_pos[1024,j] - (bn[j]+q)*n_neg[1024,j] ]
// gp/gn = log2(n_param), interleaved columns (2j = pos, 2j+1 = neg).

#define N_IN 1024
#define N_OUT 512
#define NB 128
#define Z 32            // r-split across grid.z
#define RPB 32          // rows per block = N_IN / Z
#define JT 64           // j tile per block
#define BT 32           // b tile per block

__global__ void init_ws_kernel(unsigned int* ws) {
    ws[0] = __float_as_uint(0.5f);   // bias weights participate in the max
}

__global__ void max_kernel(const float* __restrict__ wp, const float* __restrict__ wn,
                           const float* __restrict__ bp, const float* __restrict__ bn,
                           unsigned int* __restrict__ ws) {
    const int NW4 = (N_IN * N_OUT) / 4;
    int i = blockIdx.x * blockDim.x + threadIdx.x;
    int stride = gridDim.x * blockDim.x;
    float m = 0.0f;
    const float4* wp4 = (const float4*)wp;
    const float4* wn4 = (const float4*)wn;
    for (int idx = i; idx < NW4; idx += stride) {
        float4 a = wp4[idx];
        float4 b = wn4[idx];
        m = fmaxf(m, fmaxf(fmaxf(a.x, a.y), fmaxf(a.z, a.w)));
        m = fmaxf(m, fmaxf(fmaxf(b.x, b.y), fmaxf(b.z, b.w)));
    }
    if (i < N_OUT) { m = fmaxf(m, bp[i]); m = fmaxf(m, bn[i]); }
    #pragma unroll
    for (int off = 32; off > 0; off >>= 1)
        m = fmaxf(m, __shfl_xor(m, off));
    if ((threadIdx.x & 63) == 0)
        atomicMax(ws, __float_as_uint(m));   // values >= 0: uint order == float order
}

__launch_bounds__(256, 4)
__global__ void memristor_main(const float* __restrict__ x,
                               const float* __restrict__ wp,
                               const float* __restrict__ wn,
                               const float* __restrict__ npar,
                               const unsigned int* __restrict__ wsmax,
                               float* __restrict__ part) {
    // Wg[r][arr][grp][4]: arr 0=log2(wp+q) 1=log2(wn+q) 2=gp 3=gn; grp XOR-swizzled by r.
    // Compute reads: 16 distinct grp per wave -> 2 addrs/bank-quad (2-way, free).
    __shared__ float Wg[RPB][4][16][4];   // 32 KiB
    // Lx[r][b][2]: (L, s). Compute reads: 4 addrs/wave, 16-lane broadcast, conflict-free.
    __shared__ float Lx[RPB][BT][2];      // 8 KiB   -> total 40 KiB = 4 blocks/CU

    const float q = __uint_as_float(wsmax[0]) * (1.0f / 9.0f);

    const int j0 = blockIdx.x * JT;
    const int b0 = blockIdx.y * BT;
    const int rbase = blockIdx.z * RPB;
    const int tid = threadIdx.x;

    // ---------------- staging (once per block) ----------------
    {
        // x tile: 32 b x 32 r; one float4 along r per thread
        int bl = tid >> 3;          // 0..31
        int rq = tid & 7;           // 0..7
        float4 v = *(const float4*)&x[(b0 + bl) * N_IN + rbase + rq * 4];
        float vv[4] = {v.x, v.y, v.z, v.w};
        #pragma unroll
        for (int k = 0; k < 4; ++k) {
            float val = vv[k];
            float s = (val > 0.0f) ? 1.0f : ((val < 0.0f) ? -1.0f : 0.0f);
            float t = fmaxf(2.0f * fabsf(val), 1e-12f);
            Lx[rq * 4 + k][bl][0] = __builtin_amdgcn_logf(t);   // log2
            Lx[rq * 4 + k][bl][1] = s;
        }
    }
    {
        // weights: 32 r-rows x 64 j-cols; 8 j-cols (2 float4 groups) per thread
        int rr = tid >> 3;          // 0..31
        int cg = tid & 7;           // 0..7
        int pg0 = (2 * cg) ^ (rr & 15);
        int pg1 = (2 * cg + 1) ^ (rr & 15);
        {
            const float* wrow = &wp[(rbase + rr) * N_OUT + j0 + cg * 8];
            float4 a = *(const float4*)&wrow[0];
            float4 b = *(const float4*)&wrow[4];
            *(float4*)&Wg[rr][0][pg0][0] = make_float4(
                __builtin_amdgcn_logf(a.x + q), __builtin_amdgcn_logf(a.y + q),
                __builtin_amdgcn_logf(a.z + q), __builtin_amdgcn_logf(a.w + q));
            *(float4*)&Wg[rr][0][pg1][0] = make_float4(
                __builtin_amdgcn_logf(b.x + q), __builtin_amdgcn_logf(b.y + q),
                __builtin_amdgcn_logf(b.z + q), __builtin_amdgcn_logf(b.w + q));
        }
        {
            const float* wrow = &wn[(rbase + rr) * N_OUT + j0 + cg * 8];
            float4 a = *(const float4*)&wrow[0];
            float4 b = *(const float4*)&wrow[4];
            *(float4*)&Wg[rr][1][pg0][0] = make_float4(
                __builtin_amdgcn_logf(a.x + q), __builtin_amdgcn_logf(a.y + q),
                __builtin_amdgcn_logf(a.z + q), __builtin_amdgcn_logf(a.w + q));
            *(float4*)&Wg[rr][1][pg1][0] = make_float4(
                __builtin_amdgcn_logf(b.x + q), __builtin_amdgcn_logf(b.y + q),
                __builtin_amdgcn_logf(b.z + q), __builtin_amdgcn_logf(b.w + q));
        }
        {
            const float* nrow = &npar[(rbase + rr) * (2 * N_OUT) + 2 * j0 + cg * 16];
            float4 f0 = *(const float4*)&nrow[0];    // p0 n0 p1 n1
            float4 f1 = *(const float4*)&nrow[4];    // p2 n2 p3 n3
            float4 f2 = *(const float4*)&nrow[8];
            float4 f3 = *(const float4*)&nrow[12];
            *(float4*)&Wg[rr][2][pg0][0] = make_float4(
                __builtin_amdgcn_logf(f0.x), __builtin_amdgcn_logf(f0.z),
                __builtin_amdgcn_logf(f1.x), __builtin_amdgcn_logf(f1.z));
            *(float4*)&Wg[rr][3][pg0][0] = make_float4(
                __builtin_amdgcn_logf(f0.y), __builtin_amdgcn_logf(f0.w),
                __builtin_amdgcn_logf(f1.y), __builtin_amdgcn_logf(f1.w));
            *(float4*)&Wg[rr][2][pg1][0] = make_float4(
                __builtin_amdgcn_logf(f2.x), __builtin_amdgcn_logf(f2.z),
                __builtin_amdgcn_logf(f3.x), __builtin_amdgcn_logf(f3.z));
            *(float4*)&Wg[rr][3][pg1][0] = make_float4(
                __builtin_amdgcn_logf(f2.y), __builtin_amdgcn_logf(f2.w),
                __builtin_amdgcn_logf(f3.y), __builtin_amdgcn_logf(f3.w));
        }
    }
    __syncthreads();

    // ---------------- compute: 2b x 4j micro-tile per thread ----------------
    const int tj4 = tid & 15;       // j group (4 cols)
    const int tb = tid >> 4;        // 0..15
    const int bl0 = tb * 2;

    float acc0[4] = {0.f, 0.f, 0.f, 0.f};
    float acc1[4] = {0.f, 0.f, 0.f, 0.f};

    #pragma unroll 4
    for (int r = 0; r < RPB; ++r) {
        const float4* wrow = (const float4*)&Wg[r][0][tj4 ^ (r & 15)][0];
        float4 lwp = wrow[0];
        float4 lwn = wrow[16];
        float4 gp  = wrow[32];
        float4 gn  = wrow[48];
        float4 l01 = *(const float4*)&Lx[r][bl0][0];   // (L0,s0,L1,s1)
        float lwpv[4] = {lwp.x, lwp.y, lwp.z, lwp.w};
        float lwnv[4] = {lwn.x, lwn.y, lwn.z, lwn.w};
        float gpv[4]  = {gp.x, gp.y, gp.z, gp.w};
        float gnv[4]  = {gn.x, gn.y, gn.z, gn.w};
        #pragma unroll
        for (int jj = 0; jj < 4; ++jj) {
            float ep0 = __builtin_amdgcn_exp2f(fmaf(l01.x, gpv[jj], lwpv[jj]));
            float en0 = __builtin_amdgcn_exp2f(fmaf(l01.x, gnv[jj], lwnv[jj]));
            acc0[jj] = fmaf(l01.y, ep0 - en0, acc0[jj]);
            float ep1 = __builtin_amdgcn_exp2f(fmaf(l01.z, gpv[jj], lwpv[jj]));
            float en1 = __builtin_amdgcn_exp2f(fmaf(l01.z, gnv[jj], lwnv[jj]));
            acc1[jj] = fmaf(l01.w, ep1 - en1, acc1[jj]);
        }
    }

    float* p0 = &part[(size_t)blockIdx.z * (NB * N_OUT) + (b0 + bl0) * N_OUT + j0 + tj4 * 4];
    *(float4*)&p0[0]     = make_float4(acc0[0], acc0[1], acc0[2], acc0[3]);
    *(float4*)&p0[N_OUT] = make_float4(acc1[0], acc1[1], acc1[2], acc1[3]);
}

__global__ void reduce_kernel(const float* __restrict__ part,
                              const float* __restrict__ bp, const float* __restrict__ bn,
                              const float* __restrict__ npar,
                              const unsigned int* __restrict__ wsmax,
                              float* __restrict__ out) {
    int g = blockIdx.x * blockDim.x + threadIdx.x;   // float4 index, 0..16383
    const float4* p4 = (const float4*)part;
    float sx = 0.f, sy = 0.f, sz = 0.f, sw = 0.f;
    #pragma unroll 8
    for (int z = 0; z < Z; ++z) {
        float4 v = p4[(size_t)z * (NB * N_OUT / 4) + g];
        sx += v.x; sy += v.y; sz += v.z; sw += v.w;
    }
    int o = g * 4;
    int j = o & (N_OUT - 1);
    const float q = __uint_as_float(wsmax[0]) * (1.0f / 9.0f);
    float4 bpv = *(const float4*)&bp[j];
    float4 bnv = *(const float4*)&bn[j];
    const float* nrow = &npar[N_IN * (2 * N_OUT) + 2 * j];
    float4 n0 = *(const float4*)&nrow[0];
    float4 n1 = *(const float4*)&nrow[4];
    sx += (bpv.x + q) * n0.x - (bnv.x + q) * n0.y;
    sy += (bpv.y + q) * n0.z - (bnv.y + q) * n0.w;
    sz += (bpv.z + q) * n1.x - (bnv.z + q) * n1.y;
    sw += (bpv.w + q) * n1.z - (bnv.w + q) * n1.w;
    ((float4*)out)[g] = make_float4(0.5f * sx, 0.5f * sy, 0.5f * sz, 0.5f * sw);
}

extern "C" void kernel_launch(void* const* d_in, const int* in_sizes, int n_in,
                              void* d_out, int out_size, void* d_ws, size_t ws_size,
                              hipStream_t stream) {
    const float* x    = (const float*)d_in[0];
    const float* wp   = (const float*)d_in[1];
    const float* wn   = (const float*)d_in[2];
    const float* bp   = (const float*)d_in[3];
    const float* bn   = (const float*)d_in[4];
    const float* npar = (const float*)d_in[5];
    float* out = (float*)d_out;
    unsigned int* wsmax = (unsigned int*)d_ws;
    float* part = (float*)d_ws + 64;   // 256 B offset; Z*65536 floats = 8 MiB scratch

    init_ws_kernel<<<1, 1, 0, stream>>>(wsmax);
    max_kernel<<<256, 256, 0, stream>>>(wp, wn, bp, bn, wsmax);

    dim3 grid(N_OUT / JT, NB / BT, Z);   // 8 x 4 x 32 = 1024 blocks -> 4/CU
    memristor_main<<<grid, 256, 0, stream>>>(x, wp, wn, npar, wsmax, part);

    reduce_kernel<<<(NB * N_OUT / 4) / 256, 256, 0, stream>>>(part, bp, bn, npar, wsmax, out);
}